// Round 1
// 384.858 us; speedup vs baseline: 1.0301x; 1.0301x over previous
//
#include <hip/hip_runtime.h>
#include <cmath>

// Problem constants
#define TT 8192
#define NE 256
#define ND 7168
#define NGRP 8
#define TOPKG 4
#define TOPK 8
#define ROUTE_SCALE 2.5f

#define NKT (ND / 32)      // 224 k-tiles of 32
#define NNT (NE / 16)      // 16 n-tiles of 16

// GEMM tiling: block = 64 tokens x 256 experts, 256 threads (4 waves),
// wave = 64 tok x 64 exp = 4x4 tiles of 16x16, K split across k-slices.
#define TM 64
#define XPITCH 40          // halves per LDS row (32 + 8 pad): b128 reads 2-way alias = free
#define BSTRN ((size_t)NKT * 512)   // halves between 16-expert n-tiles in frag buffer

typedef _Float16 half8_ __attribute__((ext_vector_type(8)));
typedef _Float16 half4_ __attribute__((ext_vector_type(4)));
typedef float float4_ __attribute__((ext_vector_type(4)));

// Raw barrier: orders LDS ops only (lgkmcnt), does NOT drain vmcnt — the
// x/B register prefetches stay in flight across the barrier (AITER/HK
// pattern; __syncthreads would emit s_waitcnt vmcnt(0) and serialize the
// pipeline every chunk). Single asm so nothing can be scheduled between
// the wait and s_barrier; "memory" clobber fences LDS accesses.
#define BAR() asm volatile("s_waitcnt lgkmcnt(0)\n\ts_barrier" ::: "memory")

// ---------------------------------------------------------------------------
// w (fp32 [E][D]) -> fragment-ordered fp16 hi/lo.
// B-frag for mfma_f32_16x16x32_f16: lane holds B[k=quad*8+j][n=lane&15].
__global__ __launch_bounds__(256) void conv_w_kernel(
    const float* __restrict__ w, _Float16* __restrict__ whF,
    _Float16* __restrict__ wlF)
{
    const int gid  = blockIdx.x * 256 + threadIdx.x;   // NNT*NKT*64 total
    const int lane = gid & 63;
    const int pair = gid >> 6;            // nt*NKT + kt
    const int kt   = pair % NKT;
    const int nt   = pair / NKT;
    const int n  = nt * 16 + (lane & 15);
    const int kb = kt * 32 + (lane >> 4) * 8;
    const float* src = w + (size_t)n * ND + kb;
    const float4 v0 = *reinterpret_cast<const float4*>(src);
    const float4 v1 = *reinterpret_cast<const float4*>(src + 4);
    const float vs[8] = {v0.x, v0.y, v0.z, v0.w, v1.x, v1.y, v1.z, v1.w};
    half8_ h, l;
    #pragma unroll
    for (int j = 0; j < 8; ++j) {
        const _Float16 hi = (_Float16)vs[j];
        h[j] = hi;
        l[j] = (_Float16)(vs[j] - (float)hi);
    }
    const size_t off = ((size_t)pair * 64 + lane) * 8;
    *reinterpret_cast<half8_*>(whF + off) = h;
    *reinterpret_cast<half8_*>(wlF + off) = l;
}

// ---------------------------------------------------------------------------
// Split-fp16 MFMA GEMM, software-pipelined:
//   - LDS double buffer for x (hi/lo fp16), ONE raw barrier per 32-k chunk
//   - B frags prefetched 1 chunk ahead (registers, L2-resident source)
//   - x prefetched 2 chunks ahead (registers, HBM source)
//   - prefetches stay in flight ACROSS barriers (lgkmcnt-only wait)
// Slot convention: register slot s holds data for chunk with (chunk & 1) == s.
// Grid is 1-D; block -> (k-slice, token-tile) via XCD-slice-major swizzle so
// each XCD's 4MB L2 holds exactly one weight-frag k-slice (1.84 MB @ ksl=4).
__global__ __launch_bounds__(256, 2) void gemm_kernel(
    const float* __restrict__ x, const _Float16* __restrict__ whF,
    const _Float16* __restrict__ wlF, float* __restrict__ partial,
    int K_slice, int gsh)
{
    __shared__ _Float16 XhL[2][TM * XPITCH];
    __shared__ _Float16 XlL[2][TM * XPITCH];

    const int tid  = threadIdx.x;
    const int lane = tid & 63;
    const int nq   = tid >> 6;            // wave id -> 64-expert quarter

    // XCD swizzle: xcd = L&7 (8 XCDs, round-robin dispatch). gsh = log2(XCDs
    // per k-slice). All blocks on one XCD share a k-slice -> B L2-resident.
    const int L    = blockIdx.x;
    const int xcd  = L & 7;
    const int slot = L >> 3;
    const int ks   = xcd >> gsh;
    const int bx   = (slot << gsh) | (xcd & ((1 << gsh) - 1));

    const int t0   = bx * TM;
    const int kbeg = ks * K_slice;
    const int kt0  = kbeg >> 5;
    const int nchunks = K_slice >> 5;     // always even (28/56/112/224)

    const int q  = lane >> 4;             // quad
    const int cn = lane & 15;
    const int srow0 = tid >> 3;           // staging row (0..31)
    const int sc4   = tid & 7;            // staging float4 col

    float4_ acc[4][4];
    #pragma unroll
    for (int i = 0; i < 4; ++i)
        #pragma unroll
        for (int j = 0; j < 4; ++j) acc[i][j] = (float4_)0.0f;

    const float* xp0 = x + (size_t)(t0 + srow0) * ND + kbeg + sc4 * 4;
    const float* xp1 = xp0 + (size_t)32 * ND;
    const _Float16* bh0 = whF + (size_t)(nq * 4) * BSTRN + (size_t)kt0 * 512 + lane * 8;
    const _Float16* bl0 = wlF + (size_t)(nq * 4) * BSTRN + (size_t)kt0 * 512 + lane * 8;

    float4 xv[2][2];       // x stage regs: [slot][row-half]
    half8_ Bf[2][8];       // B frags: [slot][ntl*2 + (0=hi,1=lo)]

    // Prologue: x(0)->slot0, x(1)->slot1, B(0)->slot0; stage x(0) into LDS buf0.
    xv[0][0] = *reinterpret_cast<const float4*>(xp0);
    xv[0][1] = *reinterpret_cast<const float4*>(xp1);
    xv[1][0] = *reinterpret_cast<const float4*>(xp0 + 32);
    xv[1][1] = *reinterpret_cast<const float4*>(xp1 + 32);
    #pragma unroll
    for (int ntl = 0; ntl < 4; ++ntl) {
        Bf[0][ntl * 2 + 0] = *reinterpret_cast<const half8_*>(bh0 + (size_t)ntl * BSTRN);
        Bf[0][ntl * 2 + 1] = *reinterpret_cast<const half8_*>(bl0 + (size_t)ntl * BSTRN);
    }
    #pragma unroll
    for (int i = 0; i < 2; ++i) {
        const float4 v = xv[0][i];
        const float vs[4] = {v.x, v.y, v.z, v.w};
        half4_ h, l;
        #pragma unroll
        for (int j = 0; j < 4; ++j) {
            const _Float16 hi = (_Float16)vs[j];
            h[j] = hi; l[j] = (_Float16)(vs[j] - (float)hi);
        }
        const int soff = (srow0 + i * 32) * XPITCH + sc4 * 4;
        *reinterpret_cast<half4_*>(&XhL[0][soff]) = h;
        *reinterpret_cast<half4_*>(&XlL[0][soff]) = l;
    }
    BAR();   // x(1), B(0) remain in flight

#define STEP(P, C)                                                           \
    {                                                                        \
        if ((C) + 2 < nchunks) { /* x(C+2) -> slot P (freed: x(C) staged) */ \
            xv[P][0] = *reinterpret_cast<const float4*>(xp0 + ((C) + 2) * 32); \
            xv[P][1] = *reinterpret_cast<const float4*>(xp1 + ((C) + 2) * 32); \
        }                                                                    \
        if ((C) + 1 < nchunks) { /* B(C+1) -> slot P^1 */                    \
            _Pragma("unroll")                                                \
            for (int ntl = 0; ntl < 4; ++ntl) {                              \
                Bf[(P) ^ 1][ntl * 2 + 0] = *reinterpret_cast<const half8_*>( \
                    bh0 + (size_t)ntl * BSTRN + ((C) + 1) * 512);            \
                Bf[(P) ^ 1][ntl * 2 + 1] = *reinterpret_cast<const half8_*>( \
                    bl0 + (size_t)ntl * BSTRN + ((C) + 1) * 512);            \
            }                                                                \
        }                                                                    \
        half8_ ah[4], al[4];                                                 \
        _Pragma("unroll")                                                    \
        for (int mt = 0; mt < 4; ++mt) {                                     \
            ah[mt] = *reinterpret_cast<const half8_*>(                       \
                &XhL[P][(mt * 16 + cn) * XPITCH + q * 8]);                   \
            al[mt] = *reinterpret_cast<const half8_*>(                       \
                &XlL[P][(mt * 16 + cn) * XPITCH + q * 8]);                   \
        }                                                                    \
        __builtin_amdgcn_s_setprio(1);                                       \
        _Pragma("unroll")                                                    \
        for (int mt = 0; mt < 4; ++mt)                                       \
            _Pragma("unroll")                                                \
            for (int ntl = 0; ntl < 4; ++ntl) {                              \
                acc[mt][ntl] = __builtin_amdgcn_mfma_f32_16x16x32_f16(       \
                    ah[mt], Bf[P][ntl * 2 + 0], acc[mt][ntl], 0, 0, 0);      \
                acc[mt][ntl] = __builtin_amdgcn_mfma_f32_16x16x32_f16(       \
                    al[mt], Bf[P][ntl * 2 + 0], acc[mt][ntl], 0, 0, 0);      \
                acc[mt][ntl] = __builtin_amdgcn_mfma_f32_16x16x32_f16(       \
                    ah[mt], Bf[P][ntl * 2 + 1], acc[mt][ntl], 0, 0, 0);      \
            }                                                                \
        __builtin_amdgcn_s_setprio(0);                                       \
        if ((C) + 1 < nchunks) { /* stage x(C+1) from slot P^1 -> buf P^1 */ \
            _Pragma("unroll")                                                \
            for (int i = 0; i < 2; ++i) {                                    \
                const float4 v = xv[(P) ^ 1][i];                             \
                const float vs[4] = {v.x, v.y, v.z, v.w};                    \
                half4_ h, l;                                                 \
                _Pragma("unroll")                                            \
                for (int j = 0; j < 4; ++j) {                                \
                    const _Float16 hi = (_Float16)vs[j];                     \
                    h[j] = hi; l[j] = (_Float16)(vs[j] - (float)hi);         \
                }                                                            \
                const int soff = (srow0 + i * 32) * XPITCH + sc4 * 4;        \
                *reinterpret_cast<half4_*>(&XhL[(P) ^ 1][soff]) = h;         \
                *reinterpret_cast<half4_*>(&XlL[(P) ^ 1][soff]) = l;         \
            }                                                                \
        }                                                                    \
        BAR();                                                               \
    }

    for (int c = 0; c < nchunks; c += 2) {
        STEP(0, c)
        STEP(1, c + 1)
    }
#undef STEP

    // Epilogue: C/D layout col=lane&15, row=quad*4+reg
    #pragma unroll
    for (int mt = 0; mt < 4; ++mt)
        #pragma unroll
        for (int r = 0; r < 4; ++r) {
            const int t = t0 + mt * 16 + q * 4 + r;
            float* rowp = partial + ((size_t)ks * TT + t) * NE;
            #pragma unroll
            for (int ntl = 0; ntl < 4; ++ntl)
                rowp[nq * 64 + ntl * 16 + cn] = acc[mt][ntl][r];
        }
}

// ---------------------------------------------------------------------------
// Routing: one 64-lane wave per token; lane handles 4 experts.
__global__ __launch_bounds__(256) void routing_kernel(
    const float* __restrict__ partial, const float* __restrict__ bias,
    float* __restrict__ out_w, float* __restrict__ out_i, int kslices)
{
    const int lane = threadIdx.x & 63;
    const int t = blockIdx.x * 4 + (threadIdx.x >> 6);

    float4 a = make_float4(0.f, 0.f, 0.f, 0.f);
    for (int s = 0; s < kslices; ++s) {
        const float4 p = *reinterpret_cast<const float4*>(
            partial + ((size_t)s * TT + t) * NE + lane * 4);
        a.x += p.x; a.y += p.y; a.z += p.z; a.w += p.w;
    }
    const float4 b4 = *reinterpret_cast<const float4*>(bias + lane * 4);
    const float lg[4] = {a.x, a.y, a.z, a.w};
    const float bs[4] = {b4.x, b4.y, b4.z, b4.w};
    float sg[4], sv[4];
    #pragma unroll
    for (int j = 0; j < 4; ++j) {
        sg[j] = 1.0f / (1.0f + expf(-lg[j]));   // original sigmoid score
        sv[j] = sg[j] + bs[j];                  // biased score
    }

    // Per-group (8 lanes = 32 experts) top-2 sum
    float m1 = -1e30f, m2 = -1e30f;
    #pragma unroll
    for (int j = 0; j < 4; ++j) {
        if (sv[j] > m1)      { m2 = m1; m1 = sv[j]; }
        else if (sv[j] > m2) { m2 = sv[j]; }
    }
    #pragma unroll
    for (int off = 1; off <= 4; off <<= 1) {
        const float o1 = __shfl_xor(m1, off, 64);
        const float o2 = __shfl_xor(m2, off, 64);
        if (o1 > m1) { m2 = fmaxf(m1, o2); m1 = o1; }
        else         { m2 = fmaxf(m2, o1); }
    }
    const float gs = m1 + m2;

    // All 8 group scores on every lane; serial top-4 (lowest index on ties)
    float gv[NGRP];
    #pragma unroll
    for (int g = 0; g < NGRP; ++g) gv[g] = __shfl(gs, g * 8, 64);
    unsigned keep = 0;
    #pragma unroll
    for (int r = 0; r < TOPKG; ++r) {
        int best = 0; float bvv = -1e30f;
        #pragma unroll
        for (int g = 0; g < NGRP; ++g) {
            const bool taken = (keep >> g) & 1u;
            if (!taken && gv[g] > bvv) { bvv = gv[g]; best = g; }
        }
        keep |= 1u << best;
    }

    // Masked scores (exact 0.0f for dropped groups, matching sg*mask)
    const bool kept = (keep >> (lane >> 3)) & 1u;
    float rv[4];
    #pragma unroll
    for (int j = 0; j < 4; ++j) rv[j] = kept ? sv[j] : 0.0f;

    // 8x wave argmax extraction carrying (biased val, idx, orig sigmoid)
    float wsum = 0.f, myw = 0.f;
    int myi = 0;
    #pragma unroll
    for (int r = 0; r < TOPK; ++r) {
        float bv = -1e30f, bo = 0.f; int bi = 0x7fffffff;
        #pragma unroll
        for (int j = 0; j < 4; ++j)
            if (rv[j] > bv) { bv = rv[j]; bi = lane * 4 + j; bo = sg[j]; }
        #pragma unroll
        for (int off = 1; off < 64; off <<= 1) {
            const float ov = __shfl_xor(bv, off, 64);
            const int   oi = __shfl_xor(bi, off, 64);
            const float oo = __shfl_xor(bo, off, 64);
            if (ov > bv || (ov == bv && oi < bi)) { bv = ov; bi = oi; bo = oo; }
        }
        if ((bi >> 2) == lane) rv[bi & 3] = -1e30f;   // remove winner
        wsum += bo;
        if (lane == r) { myw = bo; myi = bi; }
    }
    const float scale = ROUTE_SCALE / wsum;
    if (lane < TOPK) {
        out_w[(size_t)t * TOPK + lane] = myw * scale;
        out_i[(size_t)t * TOPK + lane] = (float)myi;  // fp32-encoded indices
    }
}

// ---------------------------------------------------------------------------
extern "C" void kernel_launch(void* const* d_in, const int* in_sizes, int n_in,
                              void* d_out, int out_size, void* d_ws, size_t ws_size,
                              hipStream_t stream) {
    const float* x    = (const float*)d_in[0];
    const float* w    = (const float*)d_in[1];
    const float* bias = (const float*)d_in[2];

    float* out_w = (float*)d_out;
    float* out_i = (float*)d_out + (size_t)TT * TOPK;

    // ws layout: whF | wlF | partial[kslices][TT][NE]
    const size_t wfrag_bytes = (size_t)NE * ND * sizeof(_Float16);  // 3.67 MB
    _Float16* whF = (_Float16*)d_ws;
    _Float16* wlF = (_Float16*)((char*)d_ws + wfrag_bytes);
    float* partial = (float*)((char*)d_ws + 2 * wfrag_bytes);

    const size_t part1 = (size_t)TT * NE * sizeof(float);           // 8 MB
    // kslices=4: 512 blocks = exactly 2/CU resident in ONE round, and half
    // the split-K partial traffic of kslices=8. gsh = log2(8/kslices).
    int kslices = 1, gsh = 3;
    if      (ws_size >= 2 * wfrag_bytes + 4 * part1) { kslices = 4; gsh = 1; }
    else if (ws_size >= 2 * wfrag_bytes + 2 * part1) { kslices = 2; gsh = 2; }
    const int K_slice = ND / kslices;

    conv_w_kernel<<<(NNT * NKT * 64) / 256, 256, 0, stream>>>(w, whF, wlF);

    gemm_kernel<<<(TT / TM) * kslices, 256, 0, stream>>>(x, whF, wlF, partial,
                                                         K_slice, gsh);

    routing_kernel<<<TT / 4, 256, 0, stream>>>(partial, bias, out_w, out_i, kslices);
}

// Round 2
// 380.220 us; speedup vs baseline: 1.0427x; 1.0122x over previous
//
#include <hip/hip_runtime.h>
#include <cmath>

// Problem constants
#define TT 8192
#define NE 256
#define ND 7168
#define NGRP 8
#define TOPKG 4
#define TOPK 8
#define ROUTE_SCALE 2.5f

#define NKT (ND / 32)      // 224 k-tiles of 32
#define NNT (NE / 16)      // 16 n-tiles of 16

// GEMM tiling: block = 128 tokens x 256 experts, 512 threads (8 waves =
// 2 token-halves x 4 expert-quarters); each wave = 64 tok x 64 exp =
// 4x4 tiles of 16x16. K split across k-slices (blockIdx-encoded).
// vs TM=64/256thr: halves B-frag L2 traffic (941->470 MB) and halves
// barrier-sync events, at identical waves/SIMD occupancy (2).
#define TM 128
#define XPITCH 40          // halves per LDS row (32 + 8 pad): b128 reads 2-way alias = free
#define BSTRN ((size_t)NKT * 512)   // halves between 16-expert n-tiles in frag buffer

typedef _Float16 half8_ __attribute__((ext_vector_type(8)));
typedef _Float16 half4_ __attribute__((ext_vector_type(4)));
typedef float float4_ __attribute__((ext_vector_type(4)));

// Raw barrier: orders LDS ops only (lgkmcnt), does NOT drain vmcnt — the
// x/B register prefetches stay in flight across the barrier (AITER/HK
// pattern; __syncthreads would emit s_waitcnt vmcnt(0) and serialize the
// pipeline every chunk). Single asm so nothing can be scheduled between
// the wait and s_barrier; "memory" clobber fences LDS accesses.
#define BAR() asm volatile("s_waitcnt lgkmcnt(0)\n\ts_barrier" ::: "memory")

// ---------------------------------------------------------------------------
// w (fp32 [E][D]) -> fragment-ordered fp16 hi/lo.
// B-frag for mfma_f32_16x16x32_f16: lane holds B[k=quad*8+j][n=lane&15].
__global__ __launch_bounds__(256) void conv_w_kernel(
    const float* __restrict__ w, _Float16* __restrict__ whF,
    _Float16* __restrict__ wlF)
{
    const int gid  = blockIdx.x * 256 + threadIdx.x;   // NNT*NKT*64 total
    const int lane = gid & 63;
    const int pair = gid >> 6;            // nt*NKT + kt
    const int kt   = pair % NKT;
    const int nt   = pair / NKT;
    const int n  = nt * 16 + (lane & 15);
    const int kb = kt * 32 + (lane >> 4) * 8;
    const float* src = w + (size_t)n * ND + kb;
    const float4 v0 = *reinterpret_cast<const float4*>(src);
    const float4 v1 = *reinterpret_cast<const float4*>(src + 4);
    const float vs[8] = {v0.x, v0.y, v0.z, v0.w, v1.x, v1.y, v1.z, v1.w};
    half8_ h, l;
    #pragma unroll
    for (int j = 0; j < 8; ++j) {
        const _Float16 hi = (_Float16)vs[j];
        h[j] = hi;
        l[j] = (_Float16)(vs[j] - (float)hi);
    }
    const size_t off = ((size_t)pair * 64 + lane) * 8;
    *reinterpret_cast<half8_*>(whF + off) = h;
    *reinterpret_cast<half8_*>(wlF + off) = l;
}

// ---------------------------------------------------------------------------
// Split-fp16 MFMA GEMM, software-pipelined:
//   - LDS double buffer for x (hi/lo fp16), ONE raw barrier per 32-k chunk
//   - B frags prefetched 1 chunk ahead (registers, L2-resident source)
//   - x prefetched 2 chunks ahead (registers, HBM source)
//   - prefetches stay in flight ACROSS barriers (lgkmcnt-only wait)
// Slot convention: register slot s holds data for chunk with (chunk & 1) == s.
// Grid is 1-D; block -> (k-slice, token-tile) via XCD-slice-major swizzle so
// each XCD's 4MB L2 holds exactly one weight-frag k-slice (1.84 MB @ ksl=4).
__global__ __launch_bounds__(512, 2) void gemm_kernel(
    const float* __restrict__ x, const _Float16* __restrict__ whF,
    const _Float16* __restrict__ wlF, float* __restrict__ partial,
    int K_slice, int gsh)
{
    __shared__ _Float16 XhL[2][TM * XPITCH];   // 2 x 128x40 halves = 20 KB ea
    __shared__ _Float16 XlL[2][TM * XPITCH];   // total 80 KB -> 1 block/CU

    const int tid  = threadIdx.x;
    const int lane = tid & 63;
    const int wid  = tid >> 6;            // 0..7
    const int nq   = wid & 3;             // expert-quarter
    const int th   = wid >> 2;            // token-half (0/1)

    // XCD swizzle: xcd = L&7 (8 XCDs, round-robin dispatch). gsh = log2(XCDs
    // per k-slice). All blocks on one XCD share a k-slice -> B L2-resident.
    const int L    = blockIdx.x;
    const int xcd  = L & 7;
    const int slot = L >> 3;
    const int ks   = xcd >> gsh;
    const int bx   = (slot << gsh) | (xcd & ((1 << gsh) - 1));

    const int t0   = bx * TM;
    const int kbeg = ks * K_slice;
    const int kt0  = kbeg >> 5;
    const int nchunks = K_slice >> 5;     // always even (56/112/224)

    const int q  = lane >> 4;             // quad
    const int cn = lane & 15;
    const int srow0 = tid >> 3;           // staging row (0..63)
    const int sc4   = tid & 7;            // staging float4 col

    float4_ acc[4][4];
    #pragma unroll
    for (int i = 0; i < 4; ++i)
        #pragma unroll
        for (int j = 0; j < 4; ++j) acc[i][j] = (float4_)0.0f;

    const float* xp0 = x + (size_t)(t0 + srow0) * ND + kbeg + sc4 * 4;
    const float* xp1 = xp0 + (size_t)64 * ND;
    const _Float16* bh0 = whF + (size_t)(nq * 4) * BSTRN + (size_t)kt0 * 512 + lane * 8;
    const _Float16* bl0 = wlF + (size_t)(nq * 4) * BSTRN + (size_t)kt0 * 512 + lane * 8;

    float4 xv[2][2];       // x stage regs: [slot][row-half]
    half8_ Bf[2][8];       // B frags: [slot][ntl*2 + (0=hi,1=lo)]

    // Prologue: x(0)->slot0, x(1)->slot1, B(0)->slot0; stage x(0) into LDS buf0.
    xv[0][0] = *reinterpret_cast<const float4*>(xp0);
    xv[0][1] = *reinterpret_cast<const float4*>(xp1);
    xv[1][0] = *reinterpret_cast<const float4*>(xp0 + 32);
    xv[1][1] = *reinterpret_cast<const float4*>(xp1 + 32);
    #pragma unroll
    for (int ntl = 0; ntl < 4; ++ntl) {
        Bf[0][ntl * 2 + 0] = *reinterpret_cast<const half8_*>(bh0 + (size_t)ntl * BSTRN);
        Bf[0][ntl * 2 + 1] = *reinterpret_cast<const half8_*>(bl0 + (size_t)ntl * BSTRN);
    }
    #pragma unroll
    for (int i = 0; i < 2; ++i) {
        const float4 v = xv[0][i];
        const float vs[4] = {v.x, v.y, v.z, v.w};
        half4_ h, l;
        #pragma unroll
        for (int j = 0; j < 4; ++j) {
            const _Float16 hi = (_Float16)vs[j];
            h[j] = hi; l[j] = (_Float16)(vs[j] - (float)hi);
        }
        const int soff = (srow0 + i * 64) * XPITCH + sc4 * 4;
        *reinterpret_cast<half4_*>(&XhL[0][soff]) = h;
        *reinterpret_cast<half4_*>(&XlL[0][soff]) = l;
    }
    BAR();   // x(1), B(0) remain in flight

#define STEP(P, C)                                                           \
    {                                                                        \
        if ((C) + 2 < nchunks) { /* x(C+2) -> slot P (freed: x(C) staged) */ \
            xv[P][0] = *reinterpret_cast<const float4*>(xp0 + ((C) + 2) * 32); \
            xv[P][1] = *reinterpret_cast<const float4*>(xp1 + ((C) + 2) * 32); \
        }                                                                    \
        if ((C) + 1 < nchunks) { /* B(C+1) -> slot P^1 */                    \
            _Pragma("unroll")                                                \
            for (int ntl = 0; ntl < 4; ++ntl) {                              \
                Bf[(P) ^ 1][ntl * 2 + 0] = *reinterpret_cast<const half8_*>( \
                    bh0 + (size_t)ntl * BSTRN + ((C) + 1) * 512);            \
                Bf[(P) ^ 1][ntl * 2 + 1] = *reinterpret_cast<const half8_*>( \
                    bl0 + (size_t)ntl * BSTRN + ((C) + 1) * 512);            \
            }                                                                \
        }                                                                    \
        half8_ ah[4], al[4];                                                 \
        _Pragma("unroll")                                                    \
        for (int mt = 0; mt < 4; ++mt) {                                     \
            ah[mt] = *reinterpret_cast<const half8_*>(                       \
                &XhL[P][(th * 64 + mt * 16 + cn) * XPITCH + q * 8]);         \
            al[mt] = *reinterpret_cast<const half8_*>(                       \
                &XlL[P][(th * 64 + mt * 16 + cn) * XPITCH + q * 8]);         \
        }                                                                    \
        __builtin_amdgcn_s_setprio(1);                                       \
        _Pragma("unroll")                                                    \
        for (int mt = 0; mt < 4; ++mt)                                       \
            _Pragma("unroll")                                                \
            for (int ntl = 0; ntl < 4; ++ntl) {                              \
                acc[mt][ntl] = __builtin_amdgcn_mfma_f32_16x16x32_f16(       \
                    ah[mt], Bf[P][ntl * 2 + 0], acc[mt][ntl], 0, 0, 0);      \
                acc[mt][ntl] = __builtin_amdgcn_mfma_f32_16x16x32_f16(       \
                    al[mt], Bf[P][ntl * 2 + 0], acc[mt][ntl], 0, 0, 0);      \
                acc[mt][ntl] = __builtin_amdgcn_mfma_f32_16x16x32_f16(       \
                    ah[mt], Bf[P][ntl * 2 + 1], acc[mt][ntl], 0, 0, 0);      \
            }                                                                \
        __builtin_amdgcn_s_setprio(0);                                       \
        if ((C) + 1 < nchunks) { /* stage x(C+1) from slot P^1 -> buf P^1 */ \
            _Pragma("unroll")                                                \
            for (int i = 0; i < 2; ++i) {                                    \
                const float4 v = xv[(P) ^ 1][i];                             \
                const float vs[4] = {v.x, v.y, v.z, v.w};                    \
                half4_ h, l;                                                 \
                _Pragma("unroll")                                            \
                for (int j = 0; j < 4; ++j) {                                \
                    const _Float16 hi = (_Float16)vs[j];                     \
                    h[j] = hi; l[j] = (_Float16)(vs[j] - (float)hi);         \
                }                                                            \
                const int soff = (srow0 + i * 64) * XPITCH + sc4 * 4;        \
                *reinterpret_cast<half4_*>(&XhL[(P) ^ 1][soff]) = h;         \
                *reinterpret_cast<half4_*>(&XlL[(P) ^ 1][soff]) = l;         \
            }                                                                \
        }                                                                    \
        BAR();                                                               \
    }

    for (int c = 0; c < nchunks; c += 2) {
        STEP(0, c)
        STEP(1, c + 1)
    }
#undef STEP

    // Epilogue: C/D layout col=lane&15, row=quad*4+reg
    #pragma unroll
    for (int mt = 0; mt < 4; ++mt)
        #pragma unroll
        for (int r = 0; r < 4; ++r) {
            const int t = t0 + th * 64 + mt * 16 + q * 4 + r;
            float* rowp = partial + ((size_t)ks * TT + t) * NE;
            #pragma unroll
            for (int ntl = 0; ntl < 4; ++ntl)
                rowp[nq * 64 + ntl * 16 + cn] = acc[mt][ntl][r];
        }
}

// ---------------------------------------------------------------------------
// Routing: one 64-lane wave per token; lane handles 4 experts.
__global__ __launch_bounds__(256) void routing_kernel(
    const float* __restrict__ partial, const float* __restrict__ bias,
    float* __restrict__ out_w, float* __restrict__ out_i, int kslices)
{
    const int lane = threadIdx.x & 63;
    const int t = blockIdx.x * 4 + (threadIdx.x >> 6);

    float4 a = make_float4(0.f, 0.f, 0.f, 0.f);
    for (int s = 0; s < kslices; ++s) {
        const float4 p = *reinterpret_cast<const float4*>(
            partial + ((size_t)s * TT + t) * NE + lane * 4);
        a.x += p.x; a.y += p.y; a.z += p.z; a.w += p.w;
    }
    const float4 b4 = *reinterpret_cast<const float4*>(bias + lane * 4);
    const float lg[4] = {a.x, a.y, a.z, a.w};
    const float bs[4] = {b4.x, b4.y, b4.z, b4.w};
    float sg[4], sv[4];
    #pragma unroll
    for (int j = 0; j < 4; ++j) {
        sg[j] = 1.0f / (1.0f + expf(-lg[j]));   // original sigmoid score
        sv[j] = sg[j] + bs[j];                  // biased score
    }

    // Per-group (8 lanes = 32 experts) top-2 sum
    float m1 = -1e30f, m2 = -1e30f;
    #pragma unroll
    for (int j = 0; j < 4; ++j) {
        if (sv[j] > m1)      { m2 = m1; m1 = sv[j]; }
        else if (sv[j] > m2) { m2 = sv[j]; }
    }
    #pragma unroll
    for (int off = 1; off <= 4; off <<= 1) {
        const float o1 = __shfl_xor(m1, off, 64);
        const float o2 = __shfl_xor(m2, off, 64);
        if (o1 > m1) { m2 = fmaxf(m1, o2); m1 = o1; }
        else         { m2 = fmaxf(m2, o1); }
    }
    const float gs = m1 + m2;

    // All 8 group scores on every lane; serial top-4 (lowest index on ties)
    float gv[NGRP];
    #pragma unroll
    for (int g = 0; g < NGRP; ++g) gv[g] = __shfl(gs, g * 8, 64);
    unsigned keep = 0;
    #pragma unroll
    for (int r = 0; r < TOPKG; ++r) {
        int best = 0; float bvv = -1e30f;
        #pragma unroll
        for (int g = 0; g < NGRP; ++g) {
            const bool taken = (keep >> g) & 1u;
            if (!taken && gv[g] > bvv) { bvv = gv[g]; best = g; }
        }
        keep |= 1u << best;
    }

    // Masked scores (exact 0.0f for dropped groups, matching sg*mask)
    const bool kept = (keep >> (lane >> 3)) & 1u;
    float rv[4];
    #pragma unroll
    for (int j = 0; j < 4; ++j) rv[j] = kept ? sv[j] : 0.0f;

    // 8x wave argmax extraction carrying (biased val, idx, orig sigmoid)
    float wsum = 0.f, myw = 0.f;
    int myi = 0;
    #pragma unroll
    for (int r = 0; r < TOPK; ++r) {
        float bv = -1e30f, bo = 0.f; int bi = 0x7fffffff;
        #pragma unroll
        for (int j = 0; j < 4; ++j)
            if (rv[j] > bv) { bv = rv[j]; bi = lane * 4 + j; bo = sg[j]; }
        #pragma unroll
        for (int off = 1; off < 64; off <<= 1) {
            const float ov = __shfl_xor(bv, off, 64);
            const int   oi = __shfl_xor(bi, off, 64);
            const float oo = __shfl_xor(bo, off, 64);
            if (ov > bv || (ov == bv && oi < bi)) { bv = ov; bi = oi; bo = oo; }
        }
        if ((bi >> 2) == lane) rv[bi & 3] = -1e30f;   // remove winner
        wsum += bo;
        if (lane == r) { myw = bo; myi = bi; }
    }
    const float scale = ROUTE_SCALE / wsum;
    if (lane < TOPK) {
        out_w[(size_t)t * TOPK + lane] = myw * scale;
        out_i[(size_t)t * TOPK + lane] = (float)myi;  // fp32-encoded indices
    }
}

// ---------------------------------------------------------------------------
extern "C" void kernel_launch(void* const* d_in, const int* in_sizes, int n_in,
                              void* d_out, int out_size, void* d_ws, size_t ws_size,
                              hipStream_t stream) {
    const float* x    = (const float*)d_in[0];
    const float* w    = (const float*)d_in[1];
    const float* bias = (const float*)d_in[2];

    float* out_w = (float*)d_out;
    float* out_i = (float*)d_out + (size_t)TT * TOPK;

    // ws layout: whF | wlF | partial[kslices][TT][NE]
    const size_t wfrag_bytes = (size_t)NE * ND * sizeof(_Float16);  // 3.67 MB
    _Float16* whF = (_Float16*)d_ws;
    _Float16* wlF = (_Float16*)((char*)d_ws + wfrag_bytes);
    float* partial = (float*)((char*)d_ws + 2 * wfrag_bytes);

    const size_t part1 = (size_t)TT * NE * sizeof(float);           // 8 MB
    // kslices=4: 256 blocks of 512 thr = exactly 1/CU in ONE round.
    // gsh = log2(8/kslices) XCDs share a k-slice.
    int kslices = 1, gsh = 3;
    if      (ws_size >= 2 * wfrag_bytes + 4 * part1) { kslices = 4; gsh = 1; }
    else if (ws_size >= 2 * wfrag_bytes + 2 * part1) { kslices = 2; gsh = 2; }
    const int K_slice = ND / kslices;

    conv_w_kernel<<<(NNT * NKT * 64) / 256, 256, 0, stream>>>(w, whF, wlF);

    gemm_kernel<<<(TT / TM) * kslices, 512, 0, stream>>>(x, whF, wlF, partial,
                                                         K_slice, gsh);

    routing_kernel<<<TT / 4, 256, 0, stream>>>(partial, bias, out_w, out_i, kslices);
}

// Round 3
// 378.604 us; speedup vs baseline: 1.0471x; 1.0043x over previous
//
#include <hip/hip_runtime.h>
#include <cmath>

// Problem constants
#define TT 8192
#define NE 256
#define ND 7168
#define NGRP 8
#define TOPKG 4
#define TOPK 8
#define ROUTE_SCALE 2.5f

#define NT32 (NE / 32)     // 8 n-tiles of 32 experts
#define NK16 (ND / 16)     // 448 k-windows of 16

// GEMM tiling: block = 128 tokens x 256 experts, 512 threads (8 waves =
// 2 token-halves x 4 expert-quarters); each wave = 64 tok x 64 exp =
// 2x2 tiles of 32x32, MFMA shape 32x32x16 (2382 TF ubench vs 2075 for
// 16x16x32: same FLOPs in half the instructions, -13% MFMA pipe time).
#define TM 128
#define XPITCH 40          // halves per LDS row (32 + 8 pad): b128 reads 2-way alias = free
#define BSTRN2 ((size_t)NK16 * 512)  // halves between 32-expert n-tiles in frag buffer

typedef _Float16 half8_ __attribute__((ext_vector_type(8)));
typedef _Float16 half4_ __attribute__((ext_vector_type(4)));
typedef float float16_ __attribute__((ext_vector_type(16)));

// Raw barrier: orders LDS ops only (lgkmcnt), does NOT drain vmcnt — the
// x/B register prefetches stay in flight across the barrier. Single asm so
// nothing can slip between the wait and s_barrier.
#define BAR() asm volatile("s_waitcnt lgkmcnt(0)\n\ts_barrier" ::: "memory")

// ---------------------------------------------------------------------------
// w (fp32 [E][D]) -> fragment-ordered fp16 hi/lo for mfma_f32_32x32x16_f16.
// B-frag: lane holds B[n = nt*32 + (lane&31)][k = kk*16 + (lane>>5)*8 + j].
__global__ __launch_bounds__(256) void conv_w_kernel(
    const float* __restrict__ w, _Float16* __restrict__ whF,
    _Float16* __restrict__ wlF)
{
    const int gid  = blockIdx.x * 256 + threadIdx.x;   // NT32*NK16*64 total
    const int lane = gid & 63;
    const int pair = gid >> 6;            // nt*NK16 + kk
    const int kk   = pair % NK16;
    const int nt   = pair / NK16;
    const int n  = nt * 32 + (lane & 31);
    const int kb = kk * 16 + (lane >> 5) * 8;
    const float* src = w + (size_t)n * ND + kb;
    const float4 v0 = *reinterpret_cast<const float4*>(src);
    const float4 v1 = *reinterpret_cast<const float4*>(src + 4);
    const float vs[8] = {v0.x, v0.y, v0.z, v0.w, v1.x, v1.y, v1.z, v1.w};
    half8_ h, l;
    #pragma unroll
    for (int j = 0; j < 8; ++j) {
        const _Float16 hi = (_Float16)vs[j];
        h[j] = hi;
        l[j] = (_Float16)(vs[j] - (float)hi);
    }
    const size_t off = ((size_t)pair * 64 + lane) * 8;
    *reinterpret_cast<half8_*>(whF + off) = h;
    *reinterpret_cast<half8_*>(wlF + off) = l;
}

// ---------------------------------------------------------------------------
// Split-fp16 MFMA GEMM (32x32x16), software-pipelined:
//   - LDS double buffer for x (hi/lo fp16), ONE raw barrier per 32-k chunk
//   - B frags prefetched 1 chunk ahead (registers, L2-resident source)
//   - x prefetched 2 chunks ahead (registers, HBM source)
//   - prefetches stay in flight ACROSS barriers (lgkmcnt-only wait)
// Slot convention: register slot s holds data for chunk with (chunk & 1) == s.
// Grid is 1-D; block -> (k-slice, token-tile) via XCD-slice-major swizzle so
// each XCD pair's L2 holds one weight-frag k-slice (1.84 MB @ ksl=4).
__global__ __launch_bounds__(512, 2) void gemm_kernel(
    const float* __restrict__ x, const _Float16* __restrict__ whF,
    const _Float16* __restrict__ wlF, float* __restrict__ partial,
    int K_slice, int gsh)
{
    __shared__ _Float16 XhL[2][TM * XPITCH];   // 2 x 128x40 halves = 20 KB ea
    __shared__ _Float16 XlL[2][TM * XPITCH];   // total 80 KB -> 1 block/CU

    const int tid  = threadIdx.x;
    const int lane = tid & 63;
    const int wid  = tid >> 6;            // 0..7
    const int nq   = wid & 3;             // expert-quarter (64 experts)
    const int th   = wid >> 2;            // token-half (0/1)

    // XCD swizzle: xcd = L&7 (8 XCDs, round-robin dispatch). gsh = log2(XCDs
    // per k-slice). All blocks on one XCD share a k-slice -> B L2-resident.
    const int L    = blockIdx.x;
    const int xcd  = L & 7;
    const int slot = L >> 3;
    const int ks   = xcd >> gsh;
    const int bx   = (slot << gsh) | (xcd & ((1 << gsh) - 1));

    const int t0   = bx * TM;
    const int kbeg = ks * K_slice;
    const int kk0  = kbeg >> 4;           // first 16-k window of this slice
    const int nchunks = K_slice >> 5;     // always even (56/112/224)

    const int q5 = lane >> 5;             // k-half selector (0/1)
    const int cn = lane & 31;             // row/col within 32
    const int srow0 = tid >> 3;           // staging row (0..63)
    const int sc4   = tid & 7;            // staging float4 col

    float16_ acc[2][2];
    #pragma unroll
    for (int i = 0; i < 2; ++i)
        #pragma unroll
        for (int j = 0; j < 2; ++j) acc[i][j] = (float16_)0.0f;

    const float* xp0 = x + (size_t)(t0 + srow0) * ND + kbeg + sc4 * 4;
    const float* xp1 = xp0 + (size_t)64 * ND;
    const _Float16* bh0 = whF + (size_t)(nq * 2) * BSTRN2 + (size_t)kk0 * 512 + lane * 8;
    const _Float16* bl0 = wlF + (size_t)(nq * 2) * BSTRN2 + (size_t)kk0 * 512 + lane * 8;

    float4 xv[2][2];       // x stage regs: [slot][row-half]
    half8_ Bf[2][8];       // B frags: [slot][nt2*4 + s*2 + (0=hi,1=lo)]

    // Prologue: x(0)->slot0, x(1)->slot1, B(0)->slot0; stage x(0) into LDS buf0.
    xv[0][0] = *reinterpret_cast<const float4*>(xp0);
    xv[0][1] = *reinterpret_cast<const float4*>(xp1);
    xv[1][0] = *reinterpret_cast<const float4*>(xp0 + 32);
    xv[1][1] = *reinterpret_cast<const float4*>(xp1 + 32);
    #pragma unroll
    for (int nt2 = 0; nt2 < 2; ++nt2)
        #pragma unroll
        for (int s = 0; s < 2; ++s) {
            Bf[0][nt2 * 4 + s * 2 + 0] = *reinterpret_cast<const half8_*>(
                bh0 + (size_t)nt2 * BSTRN2 + s * 512);
            Bf[0][nt2 * 4 + s * 2 + 1] = *reinterpret_cast<const half8_*>(
                bl0 + (size_t)nt2 * BSTRN2 + s * 512);
        }
    #pragma unroll
    for (int i = 0; i < 2; ++i) {
        const float4 v = xv[0][i];
        const float vs[4] = {v.x, v.y, v.z, v.w};
        half4_ h, l;
        #pragma unroll
        for (int j = 0; j < 4; ++j) {
            const _Float16 hi = (_Float16)vs[j];
            h[j] = hi; l[j] = (_Float16)(vs[j] - (float)hi);
        }
        const int soff = (srow0 + i * 64) * XPITCH + sc4 * 4;
        *reinterpret_cast<half4_*>(&XhL[0][soff]) = h;
        *reinterpret_cast<half4_*>(&XlL[0][soff]) = l;
    }
    BAR();   // x(1), B(0) remain in flight

#define STEP(P, C)                                                           \
    {                                                                        \
        if ((C) + 2 < nchunks) { /* x(C+2) -> slot P (freed: x(C) staged) */ \
            xv[P][0] = *reinterpret_cast<const float4*>(xp0 + ((C) + 2) * 32); \
            xv[P][1] = *reinterpret_cast<const float4*>(xp1 + ((C) + 2) * 32); \
        }                                                                    \
        if ((C) + 1 < nchunks) { /* B(C+1) -> slot P^1 */                    \
            _Pragma("unroll")                                                \
            for (int nt2 = 0; nt2 < 2; ++nt2)                                \
                _Pragma("unroll")                                            \
                for (int s = 0; s < 2; ++s) {                                \
                    Bf[(P) ^ 1][nt2 * 4 + s * 2 + 0] =                       \
                        *reinterpret_cast<const half8_*>(                    \
                            bh0 + (size_t)nt2 * BSTRN2 +                     \
                            (2 * ((C) + 1) + s) * 512);                      \
                    Bf[(P) ^ 1][nt2 * 4 + s * 2 + 1] =                       \
                        *reinterpret_cast<const half8_*>(                    \
                            bl0 + (size_t)nt2 * BSTRN2 +                     \
                            (2 * ((C) + 1) + s) * 512);                      \
                }                                                            \
        }                                                                    \
        half8_ ah[2][2], al[2][2]; /* [rowtile][k-sub] */                    \
        _Pragma("unroll")                                                    \
        for (int rt = 0; rt < 2; ++rt)                                       \
            _Pragma("unroll")                                                \
            for (int s = 0; s < 2; ++s) {                                    \
                const int ro = (th * 64 + rt * 32 + cn) * XPITCH             \
                               + s * 16 + q5 * 8;                            \
                ah[rt][s] = *reinterpret_cast<const half8_*>(&XhL[P][ro]);   \
                al[rt][s] = *reinterpret_cast<const half8_*>(&XlL[P][ro]);   \
            }                                                                \
        __builtin_amdgcn_s_setprio(1);                                       \
        _Pragma("unroll")                                                    \
        for (int rt = 0; rt < 2; ++rt)                                       \
            _Pragma("unroll")                                                \
            for (int nt2 = 0; nt2 < 2; ++nt2)                                \
                _Pragma("unroll")                                            \
                for (int s = 0; s < 2; ++s) {                                \
                    acc[rt][nt2] = __builtin_amdgcn_mfma_f32_32x32x16_f16(   \
                        ah[rt][s], Bf[P][nt2 * 4 + s * 2 + 0],               \
                        acc[rt][nt2], 0, 0, 0);                              \
                    acc[rt][nt2] = __builtin_amdgcn_mfma_f32_32x32x16_f16(   \
                        al[rt][s], Bf[P][nt2 * 4 + s * 2 + 0],               \
                        acc[rt][nt2], 0, 0, 0);                              \
                    acc[rt][nt2] = __builtin_amdgcn_mfma_f32_32x32x16_f16(   \
                        ah[rt][s], Bf[P][nt2 * 4 + s * 2 + 1],               \
                        acc[rt][nt2], 0, 0, 0);                              \
                }                                                            \
        __builtin_amdgcn_s_setprio(0);                                       \
        if ((C) + 1 < nchunks) { /* stage x(C+1) from slot P^1 -> buf P^1 */ \
            _Pragma("unroll")                                                \
            for (int i = 0; i < 2; ++i) {                                    \
                const float4 v = xv[(P) ^ 1][i];                             \
                const float vs[4] = {v.x, v.y, v.z, v.w};                    \
                half4_ h, l;                                                 \
                _Pragma("unroll")                                            \
                for (int j = 0; j < 4; ++j) {                                \
                    const _Float16 hi = (_Float16)vs[j];                     \
                    h[j] = hi; l[j] = (_Float16)(vs[j] - (float)hi);         \
                }                                                            \
                const int soff = (srow0 + i * 64) * XPITCH + sc4 * 4;        \
                *reinterpret_cast<half4_*>(&XhL[(P) ^ 1][soff]) = h;         \
                *reinterpret_cast<half4_*>(&XlL[(P) ^ 1][soff]) = l;         \
            }                                                                \
        }                                                                    \
        BAR();                                                               \
    }

    for (int c = 0; c < nchunks; c += 2) {
        STEP(0, c)
        STEP(1, c + 1)
    }
#undef STEP

    // Epilogue: 32x32 C/D layout col=lane&31, row=(reg&3)+8*(reg>>2)+4*(lane>>5)
    #pragma unroll
    for (int rt = 0; rt < 2; ++rt)
        #pragma unroll
        for (int nt2 = 0; nt2 < 2; ++nt2)
            #pragma unroll
            for (int reg = 0; reg < 16; ++reg) {
                const int t = t0 + th * 64 + rt * 32 +
                              (reg & 3) + 8 * (reg >> 2) + 4 * q5;
                partial[((size_t)ks * TT + t) * NE + nq * 64 + nt2 * 32 + cn] =
                    acc[rt][nt2][reg];
            }
}

// ---------------------------------------------------------------------------
// Routing: one 64-lane wave per token; lane handles 4 experts.
__global__ __launch_bounds__(256) void routing_kernel(
    const float* __restrict__ partial, const float* __restrict__ bias,
    float* __restrict__ out_w, float* __restrict__ out_i, int kslices)
{
    const int lane = threadIdx.x & 63;
    const int t = blockIdx.x * 4 + (threadIdx.x >> 6);

    float4 a = make_float4(0.f, 0.f, 0.f, 0.f);
    for (int s = 0; s < kslices; ++s) {
        const float4 p = *reinterpret_cast<const float4*>(
            partial + ((size_t)s * TT + t) * NE + lane * 4);
        a.x += p.x; a.y += p.y; a.z += p.z; a.w += p.w;
    }
    const float4 b4 = *reinterpret_cast<const float4*>(bias + lane * 4);
    const float lg[4] = {a.x, a.y, a.z, a.w};
    const float bs[4] = {b4.x, b4.y, b4.z, b4.w};
    float sg[4], sv[4];
    #pragma unroll
    for (int j = 0; j < 4; ++j) {
        sg[j] = 1.0f / (1.0f + expf(-lg[j]));   // original sigmoid score
        sv[j] = sg[j] + bs[j];                  // biased score
    }

    // Per-group (8 lanes = 32 experts) top-2 sum
    float m1 = -1e30f, m2 = -1e30f;
    #pragma unroll
    for (int j = 0; j < 4; ++j) {
        if (sv[j] > m1)      { m2 = m1; m1 = sv[j]; }
        else if (sv[j] > m2) { m2 = sv[j]; }
    }
    #pragma unroll
    for (int off = 1; off <= 4; off <<= 1) {
        const float o1 = __shfl_xor(m1, off, 64);
        const float o2 = __shfl_xor(m2, off, 64);
        if (o1 > m1) { m2 = fmaxf(m1, o2); m1 = o1; }
        else         { m2 = fmaxf(m2, o1); }
    }
    const float gs = m1 + m2;

    // All 8 group scores on every lane; serial top-4 (lowest index on ties)
    float gv[NGRP];
    #pragma unroll
    for (int g = 0; g < NGRP; ++g) gv[g] = __shfl(gs, g * 8, 64);
    unsigned keep = 0;
    #pragma unroll
    for (int r = 0; r < TOPKG; ++r) {
        int best = 0; float bvv = -1e30f;
        #pragma unroll
        for (int g = 0; g < NGRP; ++g) {
            const bool taken = (keep >> g) & 1u;
            if (!taken && gv[g] > bvv) { bvv = gv[g]; best = g; }
        }
        keep |= 1u << best;
    }

    // Masked scores (exact 0.0f for dropped groups, matching sg*mask)
    const bool kept = (keep >> (lane >> 3)) & 1u;
    float rv[4];
    #pragma unroll
    for (int j = 0; j < 4; ++j) rv[j] = kept ? sv[j] : 0.0f;

    // 8x wave argmax extraction carrying (biased val, idx, orig sigmoid)
    float wsum = 0.f, myw = 0.f;
    int myi = 0;
    #pragma unroll
    for (int r = 0; r < TOPK; ++r) {
        float bv = -1e30f, bo = 0.f; int bi = 0x7fffffff;
        #pragma unroll
        for (int j = 0; j < 4; ++j)
            if (rv[j] > bv) { bv = rv[j]; bi = lane * 4 + j; bo = sg[j]; }
        #pragma unroll
        for (int off = 1; off < 64; off <<= 1) {
            const float ov = __shfl_xor(bv, off, 64);
            const int   oi = __shfl_xor(bi, off, 64);
            const float oo = __shfl_xor(bo, off, 64);
            if (ov > bv || (ov == bv && oi < bi)) { bv = ov; bi = oi; bo = oo; }
        }
        if ((bi >> 2) == lane) rv[bi & 3] = -1e30f;   // remove winner
        wsum += bo;
        if (lane == r) { myw = bo; myi = bi; }
    }
    const float scale = ROUTE_SCALE / wsum;
    if (lane < TOPK) {
        out_w[(size_t)t * TOPK + lane] = myw * scale;
        out_i[(size_t)t * TOPK + lane] = (float)myi;  // fp32-encoded indices
    }
}

// ---------------------------------------------------------------------------
extern "C" void kernel_launch(void* const* d_in, const int* in_sizes, int n_in,
                              void* d_out, int out_size, void* d_ws, size_t ws_size,
                              hipStream_t stream) {
    const float* x    = (const float*)d_in[0];
    const float* w    = (const float*)d_in[1];
    const float* bias = (const float*)d_in[2];

    float* out_w = (float*)d_out;
    float* out_i = (float*)d_out + (size_t)TT * TOPK;

    // ws layout: whF | wlF | partial[kslices][TT][NE]
    const size_t wfrag_bytes = (size_t)NE * ND * sizeof(_Float16);  // 3.67 MB
    _Float16* whF = (_Float16*)d_ws;
    _Float16* wlF = (_Float16*)((char*)d_ws + wfrag_bytes);
    float* partial = (float*)((char*)d_ws + 2 * wfrag_bytes);

    const size_t part1 = (size_t)TT * NE * sizeof(float);           // 8 MB
    // kslices=4: 256 blocks of 512 thr = exactly 1/CU in ONE round.
    // gsh = log2(8/kslices) XCDs share a k-slice.
    int kslices = 1, gsh = 3;
    if      (ws_size >= 2 * wfrag_bytes + 4 * part1) { kslices = 4; gsh = 1; }
    else if (ws_size >= 2 * wfrag_bytes + 2 * part1) { kslices = 2; gsh = 2; }
    const int K_slice = ND / kslices;

    conv_w_kernel<<<(NT32 * NK16 * 64) / 256, 256, 0, stream>>>(w, whF, wlF);

    gemm_kernel<<<(TT / TM) * kslices, 512, 0, stream>>>(x, whF, wlF, partial,
                                                         K_slice, gsh);

    routing_kernel<<<TT / 4, 256, 0, stream>>>(partial, bias, out_w, out_i, kslices);
}